// Round 18
// baseline (1251.693 us; speedup 1.0000x reference)
//
#include <hip/hip_runtime.h>
#include <math.h>

#define LOG0f (-1.0e30f)
#define ACTIVE_TH (-1.0e29f)
#define PRUNE_TH (-9.0f)
#define VCAB 128
#define HSZ 4096
#define HMASK (HSZ - 1)
#define MAXN 2052
#define HEMPTY 0xFFFFFFFFu

// JAX-exact logaddexp: max + log1p(exp(-|a-b|)) in f32
__device__ __forceinline__ float lae(float a, float b) {
    float mx = fmaxf(a, b);
    float d = fabsf(a - b);
    return mx + log1pf(expf(-d));
}
// monotonic float->uint transform (order-preserving; >0 for all finite floats)
__device__ __forceinline__ unsigned mono(float f) {
    unsigned u = __float_as_uint(f);
    return (u & 0x80000000u) ? ~u : (u | 0x80000000u);
}
__device__ __forceinline__ float mono_inv(unsigned m) {
    unsigned u = (m & 0x80000000u) ? (m & 0x7FFFFFFFu) : ~m;
    return __uint_as_float(u);
}
__device__ __forceinline__ unsigned rlaneu(unsigned x, int l) {
    return (unsigned)__builtin_amdgcn_readlane((int)x, l);
}
__device__ __forceinline__ float rlanef(float x, int l) {
    return __uint_as_float(rlaneu(__float_as_uint(x), l));
}
// select a[s] from a statically-indexed 8-array (cndmask chain)
__device__ __forceinline__ unsigned sel8u(const unsigned a[8], unsigned s) {
    unsigned r = a[0];
#pragma unroll
    for (int j = 1; j < 8; ++j) r = (s == (unsigned)j) ? a[j] : r;
    return r;
}

// wave-wide max of u32, SPLIT form: 4 DPP row-max levels + 4 parallel readlanes
// + depth-2 scalar max tree.
__device__ __forceinline__ unsigned wred_max_u32(unsigned x) {
    unsigned y;
    y = (unsigned)__builtin_amdgcn_update_dpp(0, (int)x, 0x111, 0xf, 0xf, false);  // row_shr:1
    x = (y > x) ? y : x;
    y = (unsigned)__builtin_amdgcn_update_dpp(0, (int)x, 0x112, 0xf, 0xf, false);  // row_shr:2
    x = (y > x) ? y : x;
    y = (unsigned)__builtin_amdgcn_update_dpp(0, (int)x, 0x114, 0xf, 0xf, false);  // row_shr:4
    x = (y > x) ? y : x;
    y = (unsigned)__builtin_amdgcn_update_dpp(0, (int)x, 0x118, 0xf, 0xf, false);  // row_shr:8
    x = (y > x) ? y : x;  // lane 15 of each 16-row holds that row's max
    unsigned r0 = rlaneu(x, 15);
    unsigned r1 = rlaneu(x, 31);
    unsigned r2 = rlaneu(x, 47);
    unsigned r3 = rlaneu(x, 63);
    unsigned m01 = (r0 > r1) ? r0 : r1;
    unsigned m23 = (r2 > r3) ? r2 : r3;
    return (m01 > m23) ? m01 : m23;
}

#define REP8(X) X(0) X(1) X(2) X(3) X(4) X(5) X(6) X(7)
#define REP7(X) X(1) X(2) X(3) X(4) X(5) X(6) X(7)

__global__ __launch_bounds__(64)
void ctc_beam_kernel(const float* __restrict__ probs, const int* __restrict__ lengths,
                     const int* __restrict__ blank_p, int* __restrict__ out_seq,
                     int* __restrict__ out_len, int T) {
    __shared__ unsigned hsh[HSZ];        // dedup map (parent,label)->node: (hkey<<12)|id
    __shared__ unsigned nodeinfo[MAXN];  // (parent<<7)|label per node id
    __shared__ int sh_seq[256];

    const int lane = threadIdx.x;
    const int b = blockIdx.x;
    const int blank = blank_p[0];
    const int length = lengths[b];
    const float* __restrict__ P = probs + (size_t)b * T * VCAB;
    const float4* __restrict__ P4 = (const float4*)P;
    const int own = lane & 7;     // beam owned by this lane
    const int slice = lane >> 3;  // vocab slice [slice*16, +16)
    const int vbase = slice * 16;
    // ext tie-break word for slot k: cl = KLB - k  (== ~refidx); cont: ~own
    const unsigned KLB = ~(8u + (unsigned)(own * VCAB + vbase));
    const unsigned RB = ~KLB;  // = refidx base = 8 + own*128 + vbase
    const unsigned cl16v = (lane < 8) ? ~(unsigned)own : 0u;
    const unsigned M0c = mono(LOG0f);  // the LOG0-class value word

    for (int i = lane; i < HSZ; i += 64) hsh[i] = HEMPTY;
    __syncthreads();

    // packed wave-uniform metadata: A8[j]=(node<<12)|par, B8[j]=(len<<7)|last
    unsigned A8[8], B8[8];
#pragma unroll
    for (int j = 0; j < 8; ++j) { A8[j] = 0xFFFu; B8[j] = (unsigned)blank; }
    // per-lane own-beam state (lane j authoritative for beam j; others replicas)
    float pb_own = (own == 0) ? 0.0f : LOG0f;  // root: blank prob = log(1)
    float pnb_own = LOG0f;
    int len_own = 0, last_own = blank;
    unsigned node_own = 0, par_own = 0xFFFu;

    // distance-2 prefetch: s* = row t, m* = row t+1; prB pipelined one step early
    float4 s0, s1, s2, s3, m0, m1_, m2_, m3_;
    float prL, prH, mprL, mprH, prB, mprB;
    {
        int base4 = (vbase >> 2);
        s0 = P4[base4]; s1 = P4[base4 + 1]; s2 = P4[base4 + 2]; s3 = P4[base4 + 3];
        prL = P[lane]; prH = P[64 + lane];
        int t1 = (1 < length) ? 1 : 0;
        int b1 = t1 * 32 + (vbase >> 2);
        m0 = P4[b1]; m1_ = P4[b1 + 1]; m2_ = P4[b1 + 2]; m3_ = P4[b1 + 3];
        mprL = P[(size_t)t1 * VCAB + lane];
        mprH = P[(size_t)t1 * VCAB + 64 + lane];
        prB = (blank < 64) ? rlanef(prL, blank) : rlanef(prH, blank - 64);
        mprB = (blank < 64) ? rlanef(mprL, blank) : rlanef(mprH, blank - 64);
    }

#pragma clang loop unroll(disable)
    for (int t = 0; t < length; ++t) {
        // early cross-lane issue: row prob at own's last label (latency hidden below)
        float sfL = __shfl(prL, last_own & 63, 64);
        float sfH = __shfl(prH, last_own & 63, 64);
        // issue loads for row t+2 (clamped)
        const int t2 = (t + 2 < length) ? (t + 2) : (length - 1);
        float4 q0, q1, q2, q3;
        float qprL, qprH;
        {
            int base4 = t2 * 32 + (vbase >> 2);
            q0 = P4[base4]; q1 = P4[base4 + 1]; q2 = P4[base4 + 2]; q3 = P4[base4 + 3];
            qprL = P[(size_t)t2 * VCAB + lane];
            qprH = P[(size_t)t2 * VCAB + 64 + lane];
        }

        float pt_own = lae(pb_own, pnb_own);
        unsigned long long bal = __ballot(pt_own > ACTIVE_TH);
        unsigned actmask = (unsigned)bal & 0xFFu;
        bool act_own = (actmask >> own) & 1u;

        // uniform per-beam prob tables (for parent values)
#define TBL(j) float pb8_##j = rlanef(pb_own, j); float pt8_##j = rlanef(pt_own, j);
        REP8(TBL)
#undef TBL

        // own parent match by node-id identity (ids content-faithful via dedup)
        int p_own = 0;
        bool matched = false;
        {
            bool gate = act_own && (len_own > 0);
#define PM(j)                                                                   \
            {                                                                   \
                bool m_ = gate && ((actmask >> j) & 1u) &&                      \
                          ((A8[j] >> 12) == par_own);                           \
                if (m_) { p_own = j; matched = true; }                          \
            }
            REP8(PM)
#undef PM
        }
        float pbp = pb8_0, ptp = pt8_0;
        int lastp = (int)(B8[0] & 127u);
#define PSEL(j)                                                                 \
        {                                                                       \
            bool m_ = (p_own == j);                                             \
            pbp = m_ ? pb8_##j : pbp;                                           \
            ptp = m_ ? pt8_##j : ptp;                                           \
            lastp = m_ ? (int)(B8[j] & 127u) : lastp;                           \
        }
        REP7(PSEL)
#undef PSEL
        float pprev = matched ? ((last_own == lastp) ? pbp : ptp) : LOG0f;
        float prLast = (last_own < 64) ? sfL : sfH;

        float contb_own = pt_own + prB;
        float contnb_own = (len_own > 0) ? (lae(pnb_own, pprev) + prLast) : LOG0f;
        float tot_own = lae(contb_own, contnb_own);

        // labels in my slice claimed as existing children of my beam
        unsigned claimed16 = 0;
#pragma unroll
        for (int j = 0; j < 8; ++j) {
            unsigned lastj = B8[j] & 127u;
            bool mj = ((actmask >> j) & 1u) && act_own && (node_own == (A8[j] & 0xFFFu));
            bool ins = ((lastj >> 4) == (unsigned)slice);
            claimed16 |= (mj && ins) ? (1u << (lastj & 15u)) : 0u;
        }

        // candidate value-words (named); LOG0-class keys uniquified to
        // M0c-1-refidx (implements the reference's refidx tie-break in-value;
        // decode clamps perturbed winners back to LOG0f)
        unsigned kh_0, kh_1, kh_2, kh_3, kh_4, kh_5, kh_6, kh_7, kh_8, kh_9,
                 kh_10, kh_11, kh_12, kh_13, kh_14, kh_15, kh_16;
#define MAKEK(c, pv)                                                                     \
        {                                                                                \
            int v = vbase + (c);                                                         \
            float prev = (v == last_own) ? pb_own : pt_own;                              \
            float val = (pv) + prev;                                                     \
            bool bad = (v == blank) | ((pv) <= PRUNE_TH) | (!act_own) |                  \
                       (bool)((claimed16 >> (c)) & 1u);                                  \
            if (bad) val = LOG0f;                                                        \
            unsigned kk = mono(val);                                                     \
            kh_##c = (kk == M0c) ? (M0c - 1u - (RB + (unsigned)(c))) : kk;               \
        }
        MAKEK(0, s0.x) MAKEK(1, s0.y) MAKEK(2, s0.z) MAKEK(3, s0.w)
        MAKEK(4, s1.x) MAKEK(5, s1.y) MAKEK(6, s1.z) MAKEK(7, s1.w)
        MAKEK(8, s2.x) MAKEK(9, s2.y) MAKEK(10, s2.z) MAKEK(11, s2.w)
        MAKEK(12, s3.x) MAKEK(13, s3.y) MAKEK(14, s3.z) MAKEK(15, s3.w)
#undef MAKEK
        {
            unsigned kk = (lane < 8) ? mono(tot_own) : 0u;
            kh_16 = (kk == M0c) ? (M0c - 1u - (unsigned)own) : kk;
        }

        // per-lane top-3 cache as (value, cl); two ext insert chains + merges
        unsigned a1v = 0u, a1c = 0u, a2v = 0u, a2c = 0u, a3v = 0u, a3c = 0u;
        unsigned b1v = 0u, b1c = 0u, b2v = 0u, b2c = 0u, b3v = 0u, b3c = 0u;
#define CINS(c1v, c1c, c2v, c2c, c3v, c3c, V, CL)                               \
        {                                                                       \
            unsigned v_ = (V); unsigned cl_ = (CL);                             \
            bool g1 = v_ > c1v, g2 = v_ > c2v, g3 = v_ > c3v;                   \
            unsigned x1v = g1 ? v_ : c1v;  unsigned x1c = g1 ? cl_ : c1c;       \
            unsigned x2v = g1 ? c1v : (g2 ? v_ : c2v);                          \
            unsigned x2c = g1 ? c1c : (g2 ? cl_ : c2c);                         \
            c3v = (g1 | g2) ? c2v : (g3 ? v_ : c3v);                            \
            c3c = (g1 | g2) ? c2c : (g3 ? cl_ : c3c);                           \
            c1v = x1v; c1c = x1c; c2v = x2v; c2c = x2c;                         \
        }
        CINS(a1v, a1c, a2v, a2c, a3v, a3c, kh_0, KLB - 0u)
        CINS(a1v, a1c, a2v, a2c, a3v, a3c, kh_2, KLB - 2u)
        CINS(a1v, a1c, a2v, a2c, a3v, a3c, kh_4, KLB - 4u)
        CINS(a1v, a1c, a2v, a2c, a3v, a3c, kh_6, KLB - 6u)
        CINS(a1v, a1c, a2v, a2c, a3v, a3c, kh_8, KLB - 8u)
        CINS(a1v, a1c, a2v, a2c, a3v, a3c, kh_10, KLB - 10u)
        CINS(a1v, a1c, a2v, a2c, a3v, a3c, kh_12, KLB - 12u)
        CINS(a1v, a1c, a2v, a2c, a3v, a3c, kh_14, KLB - 14u)
        CINS(b1v, b1c, b2v, b2c, b3v, b3c, kh_1, KLB - 1u)
        CINS(b1v, b1c, b2v, b2c, b3v, b3c, kh_3, KLB - 3u)
        CINS(b1v, b1c, b2v, b2c, b3v, b3c, kh_5, KLB - 5u)
        CINS(b1v, b1c, b2v, b2c, b3v, b3c, kh_7, KLB - 7u)
        CINS(b1v, b1c, b2v, b2c, b3v, b3c, kh_9, KLB - 9u)
        CINS(b1v, b1c, b2v, b2c, b3v, b3c, kh_11, KLB - 11u)
        CINS(b1v, b1c, b2v, b2c, b3v, b3c, kh_13, KLB - 13u)
        CINS(b1v, b1c, b2v, b2c, b3v, b3c, kh_15, KLB - 15u)
#undef CINS
#define GTE(xv, xc, yv, yc) (((xv) > (yv)) || ((xv) == (yv) && (xc) > (yc)))
        // exact merge of the two ext top-3 chains
        unsigned p1v, p1c, p2v, p2c, p3v, p3c;
        {
            bool gA = GTE(a1v, a1c, b1v, b1c);
            p1v = gA ? a1v : b1v; p1c = gA ? a1c : b1c;
            unsigned uv = gA ? b1v : a1v, uc = gA ? b1c : a1c;   // leaders' loser
            bool gS = GTE(a2v, a2c, b2v, b2c);
            unsigned vv = gS ? a2v : b2v, vc = gS ? a2c : b2c;   // seconds' winner
            unsigned wv = gS ? b2v : a2v, wc = gS ? b2c : a2c;   // seconds' loser
            bool gM = GTE(uv, uc, vv, vc);
            p2v = gM ? uv : vv; p2c = gM ? uc : vc;
            unsigned mnv = gM ? vv : uv, mnc = gM ? vc : uc;
            bool gX = GTE(a2v, a2c, b1v, b1c);
            bool gY = GTE(b2v, b2c, a1v, a1c);
            unsigned Xv = gX ? a3v : (gY ? b3v : 0u);
            unsigned Xc = gX ? a3c : (gY ? b3c : 0u);
            bool gW = GTE(wv, wc, Xv, Xc);
            unsigned Yv = gW ? wv : Xv, Yc = gW ? wc : Xc;
            bool gF = GTE(mnv, mnc, Yv, Yc);
            p3v = gF ? mnv : Yv; p3c = gF ? mnc : Yc;
        }
        // singleton merge: cont key (kh_16, cl16v) into (p1,p2,p3)
        unsigned m1v, m1cl, m2v, m2cl, m3v, m3cl;
        {
            unsigned sv = kh_16, sc = cl16v;
            bool gs1 = GTE(sv, sc, p1v, p1c);
            bool gs2 = GTE(sv, sc, p2v, p2c);
            bool gs3 = GTE(sv, sc, p3v, p3c);
            m1v = gs1 ? sv : p1v;  m1cl = gs1 ? sc : p1c;
            m2v = gs1 ? p1v : (gs2 ? sv : p2v);
            m2cl = gs1 ? p1c : (gs2 ? sc : p2c);
            m3v = gs2 ? p2v : (gs3 ? sv : p3v);
            m3cl = gs2 ? p2c : (gs3 ? sc : p3c);
        }
#undef GTE

        // continuation-value tables BEFORE rounds (latency hidden under rounds)
#define CBT(j) float cb8_##j = rlanef(contb_own, j); float cn8_##j = rlanef(contnb_own, j);
        REP8(CBT)
#undef CBT

        // top-8 extraction, SPECULATIVE rounds: keys unique on real data, so
        // won == (m1v == M); the L/identity path runs in the shadow. Cross-lane
        // value ties (adversarial) set badflag -> exact cold redo below.
        unsigned myM = 0u, myL = 0u;
        unsigned badflag = 0u;
#define RS1(k)                                                                  \
        {                                                                       \
            unsigned kv = kh_##k; unsigned kcl = KLB - (unsigned)(k);           \
            bool below = (kv < M) | ((kv == M) & (kcl < L));                    \
            bool bet = below & ((kv > bv) | ((kv == bv) & (kcl > bcl)));        \
            bv = bet ? kv : bv; bcl = bet ? kcl : bcl;                          \
        }
#define ROUND(r)                                                                \
        do {                                                                    \
            unsigned M = wred_max_u32(m1v);                                     \
            bool won = (m1v == M);                                              \
            unsigned long long tb = __ballot(won);                              \
            badflag |= (unsigned)(__builtin_popcountll(tb) != 1);               \
            unsigned L = rlaneu(m1cl, (int)__builtin_ctzll(tb));                \
            bool mine = (own == (r));                                           \
            myM = mine ? M : myM;                                               \
            myL = mine ? L : myL;                                               \
            m1v = won ? m2v : m1v; m1cl = won ? m2cl : m1cl;                    \
            m2v = won ? m3v : m2v; m2cl = won ? m3cl : m2cl;                    \
            m3v = won ? 0u : m3v;  m3cl = won ? 0u : m3cl;                      \
            bool under = won & (m1v == 0u);                                     \
            if (__any(under)) {                                                 \
                if (under) {  /* refill: best key strictly below (M,L) */       \
                    unsigned bv = 0u, bcl = 0u;                                 \
                    RS1(0) RS1(1) RS1(2) RS1(3) RS1(4) RS1(5) RS1(6) RS1(7)     \
                    RS1(8) RS1(9) RS1(10) RS1(11) RS1(12) RS1(13) RS1(14)       \
                    RS1(15)                                                     \
                    {                                                           \
                        unsigned kv = kh_16; unsigned kcl = cl16v;              \
                        bool below = (kv < M) | ((kv == M) & (kcl < L));        \
                        bool bet = below &                                      \
                                   ((kv > bv) | ((kv == bv) & (kcl > bcl)));    \
                        bv = bet ? kv : bv; bcl = bet ? kcl : bcl;              \
                    }                                                           \
                    m1v = bv; m1cl = bcl;                                       \
                }                                                               \
            }                                                                   \
        } while (0);
        ROUND(0) ROUND(1) ROUND(2) ROUND(3) ROUND(4) ROUND(5) ROUND(6) ROUND(7)
#undef ROUND
#undef RS1

        // cold exact redo (cross-lane tie detected): W-bounded full-scan rounds
        if (badflag) {
            unsigned long long W = ~0ull;
#pragma clang loop unroll(disable)
            for (int r = 0; r < 8; ++r) {
                unsigned WM = (unsigned)(W >> 32), WL = (unsigned)W;
                unsigned bv = 0u, bcl = 0u;
#define RSC(k)                                                                  \
                {                                                               \
                    unsigned kv = kh_##k; unsigned kcl = KLB - (unsigned)(k);   \
                    bool below = (kv < WM) | ((kv == WM) & (kcl < WL));         \
                    bool bet = below & ((kv > bv) | ((kv == bv) & (kcl > bcl))); \
                    bv = bet ? kv : bv; bcl = bet ? kcl : bcl;                  \
                }
                RSC(0) RSC(1) RSC(2) RSC(3) RSC(4) RSC(5) RSC(6) RSC(7)
                RSC(8) RSC(9) RSC(10) RSC(11) RSC(12) RSC(13) RSC(14) RSC(15)
#undef RSC
                {
                    unsigned kv = kh_16, kcl = cl16v;
                    bool below = (kv < WM) | ((kv == WM) & (kcl < WL));
                    bool bet = below & ((kv > bv) | ((kv == bv) & (kcl > bcl)));
                    bv = bet ? kv : bv; bcl = bet ? kcl : bcl;
                }
                unsigned M = wred_max_u32(bv);
                unsigned lo2 = (bv == M) ? bcl : 0u;
                unsigned L = wred_max_u32(lo2);
                W = (((unsigned long long)M) << 32) | L;
                bool mine = (own == r);
                myM = mine ? M : myM;
                myL = mine ? L : myL;
            }
        }

        // per-lane decode of round `own` (lanes 8..63 = replicas of beam own)
        unsigned sel = ~myL;
        bool iscont = sel < 8u;
        unsigned e = sel - 8u;
        unsigned s = iscont ? sel : (e >> 7);
        unsigned lab = e & 127u;
        unsigned Asel = sel8u(A8, s);
        unsigned Bsel = sel8u(B8, s);
        unsigned nd = Asel >> 12;
        unsigned ln = Bsel >> 7;
        float cbs, cns;
        {
            cbs = cb8_0; cns = cn8_0;
            cbs = (s == 1u) ? cb8_1 : cbs; cns = (s == 1u) ? cn8_1 : cns;
            cbs = (s == 2u) ? cb8_2 : cbs; cns = (s == 2u) ? cn8_2 : cns;
            cbs = (s == 3u) ? cb8_3 : cbs; cns = (s == 3u) ? cn8_3 : cns;
            cbs = (s == 4u) ? cb8_4 : cbs; cns = (s == 4u) ? cn8_4 : cns;
            cbs = (s == 5u) ? cb8_5 : cbs; cns = (s == 5u) ? cn8_5 : cns;
            cbs = (s == 6u) ? cb8_6 : cbs; cns = (s == 6u) ? cn8_6 : cns;
            cbs = (s == 7u) ? cb8_7 : cbs; cns = (s == 7u) ? cn8_7 : cns;
        }
        // clamp perturbed LOG0-class winners back to exact LOG0f
        bool isL0 = (M0c - myM) <= 1100u;  // unsigned wrap -> false when myM > M0c
        float extval = isL0 ? LOG0f : mono_inv(myM);
        float npb_own = iscont ? cbs : LOG0f;
        float npnb_own = iscont ? cns : extval;  // ext pnb == sort value bitwise
        unsigned A_new = iscont ? Asel : nd;  // ext: node-field=0 (patched), par=nd
        unsigned B_new = iscont ? Bsel : (((ln + 1u) << 7) | lab);
        unsigned long long extbal = __ballot(!iscont);
        unsigned extmask = (unsigned)extbal & 0xFFu;  // bit r: round r was an extension

        // dedup-hash inserts: lane r handles new beam r (deterministic pre-ids)
        unsigned insRes = 0;
        if ((extmask >> lane) & 1u) {
            unsigned preid = 1u + 8u * (unsigned)t + (unsigned)lane;
            unsigned hkey = (nd << 7) | lab;
            unsigned entry = (hkey << 12) | preid;
            unsigned h = ((hkey * 2654435761u) >> 20) & HMASK;
            for (;;) {
                unsigned prev = atomicCAS(&hsh[h], HEMPTY, entry);
                if (prev == HEMPTY) { nodeinfo[preid] = hkey; insRes = preid; break; }
                if ((prev >> 12) == hkey) { insRes = prev & 0xFFFu; break; }
                h = (h + 1) & HMASK;
            }
        }
        // own-state directly from per-lane decode (+1 shfl for the node patch)
        unsigned patched = (unsigned)__shfl((int)insRes, own, 64);
        node_own = iscont ? (A_new >> 12) : patched;
        par_own = A_new & 0xFFFu;
        len_own = (int)(B_new >> 7);
        last_own = (int)(B_new & 127u);
        pb_own = npb_own; pnb_own = npnb_own;

        // commit uniform metadata: gather from lane r; patch ext node ids
#pragma unroll
        for (int r = 0; r < 8; ++r) {
            unsigned Ar = rlaneu(A_new, r);
            unsigned Br = rlaneu(B_new, r);
            if ((extmask >> r) & 1u)  // uniform condition
                Ar = (rlaneu(insRes, r) << 12) | (Ar & 0xFFFu);
            A8[r] = Ar; B8[r] = Br;
        }

        // rotate prefetch pipeline: cur <- nx <- q; prB <- mprB; new mprB from new nx
        s0 = m0; s1 = m1_; s2 = m2_; s3 = m3_;
        prL = mprL; prH = mprH;
        prB = mprB;
        m0 = q0; m1_ = q1; m2_ = q2; m3_ = q3;
        mprL = qprL; mprH = qprH;
        mprB = (blank < 64) ? rlanef(mprL, blank) : rlanef(mprH, blank - 64);
    }

    // final argmax of totals (ties -> lowest index), then parent-walk reconstruction
    unsigned fh, fl;
    {
        float tot = lae(pb_own, pnb_own);
        fh = (lane < 8) ? mono(tot) : 0u;
        fl = (lane < 8) ? ~(unsigned)lane : 0u;
    }
    {
        unsigned M = wred_max_u32(fh);
        unsigned lo2 = (fh == M) ? fl : 0u;
        fl = wred_max_u32(lo2);
    }
    const int best = (int)(~fl);
    int L = 0;
    unsigned c = 0;
#pragma unroll
    for (int j = 0; j < 8; ++j)
        if (best == j) { L = (int)(B8[j] >> 7); c = A8[j] >> 12; }
    if (lane == 0) {
        for (int k = L - 1; k >= 0; --k) {
            unsigned info = nodeinfo[c];
            sh_seq[k] = (int)(info & 127u);
            c = info >> 7;
        }
    }
    __syncthreads();
    for (int j = lane; j < T; j += 64)
        out_seq[(size_t)b * T + j] = (j < L) ? sh_seq[j] : 0;
    if (lane == 0) out_len[b] = L;
}

extern "C" void kernel_launch(void* const* d_in, const int* in_sizes, int n_in,
                              void* d_out, int out_size, void* d_ws, size_t ws_size,
                              hipStream_t stream) {
    const float* probs = (const float*)d_in[0];
    const int* lengths = (const int*)d_in[1];
    // d_in[2] = beam_width (fixed 8, compiled in); d_in[3] = blank_index
    const int* blank_p = (const int*)d_in[3];
    const int B = in_sizes[1];
    const int T = in_sizes[0] / (B * VCAB);
    int* out = (int*)d_out;
    ctc_beam_kernel<<<B, 64, 0, stream>>>(probs, lengths, blank_p, out,
                                          out + (size_t)B * T, T);
}

// Round 19
// 1107.993 us; speedup vs baseline: 1.1297x; 1.1297x over previous
//
#include <hip/hip_runtime.h>
#include <math.h>

#define LOG0f (-1.0e30f)
#define ACTIVE_TH (-1.0e29f)
#define PRUNE_TH (-9.0f)
#define VCAB 128
#define HSZ 4096
#define HMASK (HSZ - 1)
#define MAXN 2052
#define HEMPTY 0xFFFFFFFFu

// JAX-exact logaddexp: max + log1p(exp(-|a-b|)) in f32
__device__ __forceinline__ float lae(float a, float b) {
    float mx = fmaxf(a, b);
    float d = fabsf(a - b);
    return mx + log1pf(expf(-d));
}
// monotonic float->uint transform (order-preserving; >0 for all finite floats)
__device__ __forceinline__ unsigned mono(float f) {
    unsigned u = __float_as_uint(f);
    return (u & 0x80000000u) ? ~u : (u | 0x80000000u);
}
__device__ __forceinline__ float mono_inv(unsigned m) {
    unsigned u = (m & 0x80000000u) ? (m & 0x7FFFFFFFu) : ~m;
    return __uint_as_float(u);
}
__device__ __forceinline__ unsigned rlaneu(unsigned x, int l) {
    return (unsigned)__builtin_amdgcn_readlane((int)x, l);
}
__device__ __forceinline__ float rlanef(float x, int l) {
    return __uint_as_float(rlaneu(__float_as_uint(x), l));
}
// select a[s] from a statically-indexed 8-array (cndmask chain)
__device__ __forceinline__ unsigned sel8u(const unsigned a[8], unsigned s) {
    unsigned r = a[0];
#pragma unroll
    for (int j = 1; j < 8; ++j) r = (s == (unsigned)j) ? a[j] : r;
    return r;
}

// wave-wide max of u32, SPLIT form: 4 DPP row-max levels + 4 parallel readlanes
// + depth-2 scalar max tree.
__device__ __forceinline__ unsigned wred_max_u32(unsigned x) {
    unsigned y;
    y = (unsigned)__builtin_amdgcn_update_dpp(0, (int)x, 0x111, 0xf, 0xf, false);  // row_shr:1
    x = (y > x) ? y : x;
    y = (unsigned)__builtin_amdgcn_update_dpp(0, (int)x, 0x112, 0xf, 0xf, false);  // row_shr:2
    x = (y > x) ? y : x;
    y = (unsigned)__builtin_amdgcn_update_dpp(0, (int)x, 0x114, 0xf, 0xf, false);  // row_shr:4
    x = (y > x) ? y : x;
    y = (unsigned)__builtin_amdgcn_update_dpp(0, (int)x, 0x118, 0xf, 0xf, false);  // row_shr:8
    x = (y > x) ? y : x;  // lane 15 of each 16-row holds that row's max
    unsigned r0 = rlaneu(x, 15);
    unsigned r1 = rlaneu(x, 31);
    unsigned r2 = rlaneu(x, 47);
    unsigned r3 = rlaneu(x, 63);
    unsigned m01 = (r0 > r1) ? r0 : r1;
    unsigned m23 = (r2 > r3) ? r2 : r3;
    return (m01 > m23) ? m01 : m23;
}

#define REP8(X) X(0) X(1) X(2) X(3) X(4) X(5) X(6) X(7)
#define REP7(X) X(1) X(2) X(3) X(4) X(5) X(6) X(7)
#define SEL8N(out, s, n)                                                        \
    do {                                                                        \
        out = n##_0;                                                            \
        out = ((s) == 1u) ? n##_1 : out; out = ((s) == 2u) ? n##_2 : out;       \
        out = ((s) == 3u) ? n##_3 : out; out = ((s) == 4u) ? n##_4 : out;       \
        out = ((s) == 5u) ? n##_5 : out; out = ((s) == 6u) ? n##_6 : out;       \
        out = ((s) == 7u) ? n##_7 : out;                                        \
    } while (0)

__global__ __launch_bounds__(64)
void ctc_beam_kernel(const float* __restrict__ probs, const int* __restrict__ lengths,
                     const int* __restrict__ blank_p, int* __restrict__ out_seq,
                     int* __restrict__ out_len, int T) {
    __shared__ unsigned hsh[HSZ];        // dedup map (parent,label)->node: (hkey<<12)|id
    __shared__ unsigned nodeinfo[MAXN];  // (parent<<7)|label per node id
    __shared__ int sh_seq[256];

    const int lane = threadIdx.x;
    const int b = blockIdx.x;
    const int blank = blank_p[0];
    const int length = lengths[b];
    const float* __restrict__ P = probs + (size_t)b * T * VCAB;
    const float4* __restrict__ P4 = (const float4*)P;
    const int own = lane & 7;     // beam owned by this lane
    const int slice = lane >> 3;  // vocab slice [slice*16, +16)
    const int vbase = slice * 16;
    // ext tie-break word for slot k: cl = KLB - k  (== ~refidx); cont: ~own
    const unsigned KLB = ~(8u + (unsigned)(own * VCAB + vbase));

    for (int i = lane; i < HSZ; i += 64) hsh[i] = HEMPTY;
    __syncthreads();

    // packed wave-uniform metadata: A8[j]=(node<<12)|par, B8[j]=(len<<7)|last
    unsigned A8[8], B8[8];
#pragma unroll
    for (int j = 0; j < 8; ++j) { A8[j] = 0xFFFu; B8[j] = (unsigned)blank; }
    // per-lane own-beam state (lane j authoritative for beam j; others replicas)
    float pb_own = (own == 0) ? 0.0f : LOG0f;  // root: blank prob = log(1)
    float pnb_own = LOG0f;
    int len_own = 0, last_own = blank;
    unsigned node_own = 0, par_own = 0xFFFu;

    // distance-2 prefetch: s* = row t, m* = row t+1; prB pipelined one step early
    float4 s0, s1, s2, s3, m0, m1_, m2_, m3_;
    float prL, prH, mprL, mprH, prB, mprB;
    {
        int base4 = (vbase >> 2);
        s0 = P4[base4]; s1 = P4[base4 + 1]; s2 = P4[base4 + 2]; s3 = P4[base4 + 3];
        prL = P[lane]; prH = P[64 + lane];
        int t1 = (1 < length) ? 1 : 0;
        int b1 = t1 * 32 + (vbase >> 2);
        m0 = P4[b1]; m1_ = P4[b1 + 1]; m2_ = P4[b1 + 2]; m3_ = P4[b1 + 3];
        mprL = P[(size_t)t1 * VCAB + lane];
        mprH = P[(size_t)t1 * VCAB + 64 + lane];
        prB = (blank < 64) ? rlanef(prL, blank) : rlanef(prH, blank - 64);
        mprB = (blank < 64) ? rlanef(mprL, blank) : rlanef(mprH, blank - 64);
    }

#pragma clang loop unroll(disable)
    for (int t = 0; t < length; ++t) {
        // early cross-lane issue: row prob at own's last label (latency hidden below)
        float sfL = __shfl(prL, last_own & 63, 64);
        float sfH = __shfl(prH, last_own & 63, 64);
        // issue loads for row t+2 (clamped)
        const int t2 = (t + 2 < length) ? (t + 2) : (length - 1);
        float4 q0, q1, q2, q3;
        float qprL, qprH;
        {
            int base4 = t2 * 32 + (vbase >> 2);
            q0 = P4[base4]; q1 = P4[base4 + 1]; q2 = P4[base4 + 2]; q3 = P4[base4 + 3];
            qprL = P[(size_t)t2 * VCAB + lane];
            qprH = P[(size_t)t2 * VCAB + 64 + lane];
        }

        float pt_own = lae(pb_own, pnb_own);
        unsigned long long bal = __ballot(pt_own > ACTIVE_TH);
        unsigned actmask = (unsigned)bal & 0xFFu;
        bool act_own = (actmask >> own) & 1u;

        // uniform per-beam prob tables (for parent values)
#define TBL(j) float pb8_##j = rlanef(pb_own, j); float pt8_##j = rlanef(pt_own, j);
        REP8(TBL)
#undef TBL

        // own parent match by node-id identity (ids content-faithful via dedup)
        int p_own = 0;
        bool matched = false;
        {
            bool gate = act_own && (len_own > 0);
#define PM(j)                                                                   \
            {                                                                   \
                bool m_ = gate && ((actmask >> j) & 1u) &&                      \
                          ((A8[j] >> 12) == par_own);                           \
                if (m_) { p_own = j; matched = true; }                          \
            }
            REP8(PM)
#undef PM
        }
        float pbp = pb8_0, ptp = pt8_0;
        int lastp = (int)(B8[0] & 127u);
#define PSEL(j)                                                                 \
        {                                                                       \
            bool m_ = (p_own == j);                                             \
            pbp = m_ ? pb8_##j : pbp;                                           \
            ptp = m_ ? pt8_##j : ptp;                                           \
            lastp = m_ ? (int)(B8[j] & 127u) : lastp;                           \
        }
        REP7(PSEL)
#undef PSEL
        float pprev = matched ? ((last_own == lastp) ? pbp : ptp) : LOG0f;
        float prLast = (last_own < 64) ? sfL : sfH;

        float contb_own = pt_own + prB;
        float contnb_own = (len_own > 0) ? (lae(pnb_own, pprev) + prLast) : LOG0f;
        float tot_own = lae(contb_own, contnb_own);

        // labels in my slice claimed as existing children of my beam
        unsigned claimed16 = 0;
#pragma unroll
        for (int j = 0; j < 8; ++j) {
            unsigned lastj = B8[j] & 127u;
            bool mj = ((actmask >> j) & 1u) && act_own && (node_own == (A8[j] & 0xFFFu));
            bool ins = ((lastj >> 4) == (unsigned)slice);
            claimed16 |= (mj && ins) ? (1u << (lastj & 15u)) : 0u;
        }

        // candidate value-words (named); full key = (kh, cl), cl: ext k -> KLB-k; cont -> ~own
        unsigned kh_0, kh_1, kh_2, kh_3, kh_4, kh_5, kh_6, kh_7, kh_8, kh_9,
                 kh_10, kh_11, kh_12, kh_13, kh_14, kh_15, kh_16;
#define MAKEK(c, pv)                                                                     \
        {                                                                                \
            int v = vbase + (c);                                                         \
            float prev = (v == last_own) ? pb_own : pt_own;                              \
            float val = (pv) + prev;                                                     \
            bool bad = (v == blank) | ((pv) <= PRUNE_TH) | (!act_own) |                  \
                       (bool)((claimed16 >> (c)) & 1u);                                  \
            if (bad) val = LOG0f;                                                        \
            kh_##c = mono(val);                                                          \
        }
        MAKEK(0, s0.x) MAKEK(1, s0.y) MAKEK(2, s0.z) MAKEK(3, s0.w)
        MAKEK(4, s1.x) MAKEK(5, s1.y) MAKEK(6, s1.z) MAKEK(7, s1.w)
        MAKEK(8, s2.x) MAKEK(9, s2.y) MAKEK(10, s2.z) MAKEK(11, s2.w)
        MAKEK(12, s3.x) MAKEK(13, s3.y) MAKEK(14, s3.z) MAKEK(15, s3.w)
#undef MAKEK
        kh_16 = (lane < 8) ? mono(tot_own) : 0u;

        // per-lane top-3 cache as (value, rank); rank 0=cont, k+1=ext slot k.
        // EXT-ONLY insert chains (parallel with the lae2/lae3 chain);
        // cont key merged at the end as a rank-aware singleton.
        unsigned a1v = 0u, a1p = 31u, a2v = 0u, a2p = 31u, a3v = 0u, a3p = 31u;
        unsigned b1v = 0u, b1p = 31u, b2v = 0u, b2p = 31u, b3v = 0u, b3p = 31u;
#define CINS(c1v, c1p, c2v, c2p, c3v, c3p, V, PR)                               \
        {                                                                       \
            unsigned v_ = (V); bool g1 = v_ > c1v, g2 = v_ > c2v, g3 = v_ > c3v; \
            unsigned x1v = g1 ? v_ : c1v;  unsigned x1p = g1 ? (PR) : c1p;      \
            unsigned x2v = g1 ? c1v : (g2 ? v_ : c2v);                          \
            unsigned x2p = g1 ? c1p : (g2 ? (PR) : c2p);                        \
            c3v = (g1 | g2) ? c2v : (g3 ? v_ : c3v);                            \
            c3p = (g1 | g2) ? c2p : (g3 ? (PR) : c3p);                          \
            c1v = x1v; c1p = x1p; c2v = x2v; c2p = x2p;                         \
        }
        CINS(a1v, a1p, a2v, a2p, a3v, a3p, kh_0, 1u)
        CINS(a1v, a1p, a2v, a2p, a3v, a3p, kh_2, 3u)
        CINS(a1v, a1p, a2v, a2p, a3v, a3p, kh_4, 5u)
        CINS(a1v, a1p, a2v, a2p, a3v, a3p, kh_6, 7u)
        CINS(a1v, a1p, a2v, a2p, a3v, a3p, kh_8, 9u)
        CINS(a1v, a1p, a2v, a2p, a3v, a3p, kh_10, 11u)
        CINS(a1v, a1p, a2v, a2p, a3v, a3p, kh_12, 13u)
        CINS(a1v, a1p, a2v, a2p, a3v, a3p, kh_14, 15u)
        CINS(b1v, b1p, b2v, b2p, b3v, b3p, kh_1, 2u)
        CINS(b1v, b1p, b2v, b2p, b3v, b3p, kh_3, 4u)
        CINS(b1v, b1p, b2v, b2p, b3v, b3p, kh_5, 6u)
        CINS(b1v, b1p, b2v, b2p, b3v, b3p, kh_7, 8u)
        CINS(b1v, b1p, b2v, b2p, b3v, b3p, kh_9, 10u)
        CINS(b1v, b1p, b2v, b2p, b3v, b3p, kh_11, 12u)
        CINS(b1v, b1p, b2v, b2p, b3v, b3p, kh_13, 14u)
        CINS(b1v, b1p, b2v, b2p, b3v, b3p, kh_15, 16u)
#undef CINS
#define GTE(xv, xp, yv, yp) (((xv) > (yv)) || ((xv) == (yv) && (xp) < (yp)))
        // exact merge of the two ext top-3 chains
        unsigned p1v, p1p, p2v, p2p, p3v, p3p;
        {
            bool gA = GTE(a1v, a1p, b1v, b1p);
            p1v = gA ? a1v : b1v; p1p = gA ? a1p : b1p;
            unsigned uv = gA ? b1v : a1v, up = gA ? b1p : a1p;   // leaders' loser
            bool gS = GTE(a2v, a2p, b2v, b2p);
            unsigned vv = gS ? a2v : b2v, vp = gS ? a2p : b2p;   // seconds' winner
            unsigned wv = gS ? b2v : a2v, wp = gS ? b2p : a2p;   // seconds' loser
            bool gM = GTE(uv, up, vv, vp);
            p2v = gM ? uv : vv; p2p = gM ? up : vp;
            unsigned mnv = gM ? vv : uv, mnp = gM ? vp : up;
            bool gX = GTE(a2v, a2p, b1v, b1p);
            bool gY = GTE(b2v, b2p, a1v, a1p);
            unsigned Xv = gX ? a3v : (gY ? b3v : 0u);
            unsigned Xp = gX ? a3p : (gY ? b3p : 31u);
            bool gW = GTE(wv, wp, Xv, Xp);
            unsigned Yv = gW ? wv : Xv, Yp = gW ? wp : Xp;
            bool gF = GTE(mnv, mnp, Yv, Yp);
            p3v = gF ? mnv : Yv; p3p = gF ? mnp : Yp;
        }
        // singleton merge: cont key (kh_16, rank 0) into (p1,p2,p3)
        unsigned m1v, m1p, m2v, m2p, m3v, m3p;
        {
            unsigned sv = kh_16;
            bool gs1 = GTE(sv, 0u, p1v, p1p);
            bool gs2 = GTE(sv, 0u, p2v, p2p);
            bool gs3 = GTE(sv, 0u, p3v, p3p);
            m1v = gs1 ? sv : p1v;  m1p = gs1 ? 0u : p1p;
            m2v = gs1 ? p1v : (gs2 ? sv : p2v);
            m2p = gs1 ? p1p : (gs2 ? 0u : p2p);
            m3v = gs2 ? p2v : (gs3 ? sv : p3v);
            m3p = gs2 ? p2p : (gs3 ? 0u : p3p);
        }
#undef GTE

        // continuation-value tables BEFORE rounds (latency hidden under rounds)
#define CBT(j) float cb8_##j = rlanef(contb_own, j); float cn8_##j = rlanef(contnb_own, j);
        REP8(CBT)
#undef CBT

        // top-8 extraction: submit-always, shift-on-win, refill on underflow.
        // won fast path: with a unique value-max lane (common), won == hit and
        // the L readlane moves off the inter-round chain. Rounds 0-1 cannot
        // underflow (3 wins needed), so they skip the under check entirely.
        unsigned selh_0, selh_1, selh_2, selh_3, selh_4, selh_5, selh_6, selh_7;
        unsigned sell_0, sell_1, sell_2, sell_3, sell_4, sell_5, sell_6, sell_7;
#define RS1(k)                                                                  \
        {                                                                       \
            unsigned kv = kh_##k; unsigned kcl = KLB - (unsigned)(k);           \
            bool below = (kv < M) | ((kv == M) & (kcl < L));                    \
            bool bet = below & ((kv > bv) | ((kv == bv) & (kcl > bcl)));        \
            bv = bet ? kv : bv; bp = bet ? (unsigned)((k) + 1) : bp;            \
            bcl = bet ? kcl : bcl;                                              \
        }
#define ROUND(r, DO_UNDER)                                                      \
        do {                                                                    \
            unsigned ch = m1v;                                                  \
            unsigned cl = (m1p == 0u) ? ~(unsigned)own : (KLB - (m1p - 1u));    \
            unsigned M = wred_max_u32(ch);                                      \
            bool hit = (ch == M);                                               \
            unsigned long long tb = __ballot(hit);                              \
            unsigned L;                                                         \
            bool won;                                                           \
            if (__builtin_popcountll(tb) == 1) {                                \
                won = hit;  /* single value-max lane: it wins regardless of L */\
                L = rlaneu(cl, __builtin_ctzll(tb));                            \
            } else {                                                            \
                unsigned lo2 = hit ? cl : 0u;                                   \
                L = wred_max_u32(lo2);                                          \
                won = hit & (cl == L);                                          \
            }                                                                   \
            selh_##r = M; sell_##r = L;                                         \
            m1v = won ? m2v : m1v; m1p = won ? m2p : m1p;                       \
            m2v = won ? m3v : m2v; m2p = won ? m3p : m2p;                       \
            m3v = won ? 0u : m3v;  m3p = won ? 31u : m3p;                       \
            if (DO_UNDER) {                                                     \
                bool under = won & (m1v == 0u);                                 \
                if (__any(under)) {                                             \
                    if (under) {  /* rescan: best key strictly below (M,L) */   \
                        unsigned bv = 0u, bp = 31u, bcl = 0u;                   \
                        RS1(0) RS1(1) RS1(2) RS1(3) RS1(4) RS1(5) RS1(6)        \
                        RS1(7) RS1(8) RS1(9) RS1(10) RS1(11) RS1(12) RS1(13)    \
                        RS1(14) RS1(15)                                         \
                        {                                                       \
                            unsigned kv = kh_16;                                \
                            unsigned kcl = (lane < 8) ? ~(unsigned)own : 0u;    \
                            bool below = (kv < M) | ((kv == M) & (kcl < L));    \
                            bool bet = below &                                  \
                                       ((kv > bv) | ((kv == bv) & (kcl > bcl))); \
                            bv = bet ? kv : bv; bp = bet ? 0u : bp;             \
                            bcl = bet ? kcl : bcl;                              \
                        }                                                       \
                        m1v = bv; m1p = bp;  /* bv==0 -> lane exhausted */      \
                    }                                                           \
                }                                                               \
            }                                                                   \
        } while (0);
        ROUND(0, 0) ROUND(1, 0) ROUND(2, 1) ROUND(3, 1)
        ROUND(4, 1) ROUND(5, 1) ROUND(6, 1) ROUND(7, 1)
#undef ROUND
#undef RS1

        // per-lane decode of round `own` (lanes 8..63 = replicas of beam own)
        unsigned myM, myL;
        SEL8N(myM, (unsigned)own, selh);
        SEL8N(myL, (unsigned)own, sell);
        unsigned sel = ~myL;
        bool iscont = sel < 8u;
        unsigned e = sel - 8u;
        unsigned s = iscont ? sel : (e >> 7);
        unsigned lab = e & 127u;
        unsigned Asel = sel8u(A8, s);
        unsigned Bsel = sel8u(B8, s);
        unsigned nd = Asel >> 12;
        unsigned ln = Bsel >> 7;
        float cbs, cns;
        {
            cbs = cb8_0; cns = cn8_0;
            cbs = (s == 1u) ? cb8_1 : cbs; cns = (s == 1u) ? cn8_1 : cns;
            cbs = (s == 2u) ? cb8_2 : cbs; cns = (s == 2u) ? cn8_2 : cns;
            cbs = (s == 3u) ? cb8_3 : cbs; cns = (s == 3u) ? cn8_3 : cns;
            cbs = (s == 4u) ? cb8_4 : cbs; cns = (s == 4u) ? cn8_4 : cns;
            cbs = (s == 5u) ? cb8_5 : cbs; cns = (s == 5u) ? cn8_5 : cns;
            cbs = (s == 6u) ? cb8_6 : cbs; cns = (s == 6u) ? cn8_6 : cns;
            cbs = (s == 7u) ? cb8_7 : cbs; cns = (s == 7u) ? cn8_7 : cns;
        }
        float npb_own = iscont ? cbs : LOG0f;
        float npnb_own = iscont ? cns : mono_inv(myM);  // ext pnb == sort value bitwise
        unsigned A_new = iscont ? Asel : nd;  // ext: node-field=0 (patched), par=nd
        unsigned B_new = iscont ? Bsel : (((ln + 1u) << 7) | lab);
        unsigned long long extbal = __ballot(!iscont);
        unsigned extmask = (unsigned)extbal & 0xFFu;  // bit r: round r was an extension

        // dedup-hash inserts: lane r handles new beam r (deterministic pre-ids)
        unsigned insRes = 0;
        if ((extmask >> lane) & 1u) {
            unsigned preid = 1u + 8u * (unsigned)t + (unsigned)lane;
            unsigned hkey = (nd << 7) | lab;
            unsigned entry = (hkey << 12) | preid;
            unsigned h = ((hkey * 2654435761u) >> 20) & HMASK;
            for (;;) {
                unsigned prev = atomicCAS(&hsh[h], HEMPTY, entry);
                if (prev == HEMPTY) { nodeinfo[preid] = hkey; insRes = preid; break; }
                if ((prev >> 12) == hkey) { insRes = prev & 0xFFFu; break; }
                h = (h + 1) & HMASK;
            }
        }
        // own-state directly from per-lane decode (+1 shfl for the node patch)
        unsigned patched = (unsigned)__shfl((int)insRes, own, 64);
        node_own = iscont ? (A_new >> 12) : patched;
        par_own = A_new & 0xFFFu;
        len_own = (int)(B_new >> 7);
        last_own = (int)(B_new & 127u);
        pb_own = npb_own; pnb_own = npnb_own;

        // commit uniform metadata: gather from lane r; patch ext node ids
#pragma unroll
        for (int r = 0; r < 8; ++r) {
            unsigned Ar = rlaneu(A_new, r);
            unsigned Br = rlaneu(B_new, r);
            if ((extmask >> r) & 1u)  // uniform condition
                Ar = (rlaneu(insRes, r) << 12) | (Ar & 0xFFFu);
            A8[r] = Ar; B8[r] = Br;
        }

        // rotate prefetch pipeline: cur <- nx <- q; prB <- mprB; new mprB from new nx
        s0 = m0; s1 = m1_; s2 = m2_; s3 = m3_;
        prL = mprL; prH = mprH;
        prB = mprB;
        m0 = q0; m1_ = q1; m2_ = q2; m3_ = q3;
        mprL = qprL; mprH = qprH;
        mprB = (blank < 64) ? rlanef(mprL, blank) : rlanef(mprH, blank - 64);
    }

    // final argmax of totals (ties -> lowest index), then parent-walk reconstruction
    unsigned fh, fl;
    {
        float tot = lae(pb_own, pnb_own);
        fh = (lane < 8) ? mono(tot) : 0u;
        fl = (lane < 8) ? ~(unsigned)lane : 0u;
    }
    {
        unsigned M = wred_max_u32(fh);
        unsigned lo2 = (fh == M) ? fl : 0u;
        fl = wred_max_u32(lo2);
    }
    const int best = (int)(~fl);
    int L = 0;
    unsigned c = 0;
#pragma unroll
    for (int j = 0; j < 8; ++j)
        if (best == j) { L = (int)(B8[j] >> 7); c = A8[j] >> 12; }
    if (lane == 0) {
        for (int k = L - 1; k >= 0; --k) {
            unsigned info = nodeinfo[c];
            sh_seq[k] = (int)(info & 127u);
            c = info >> 7;
        }
    }
    __syncthreads();
    for (int j = lane; j < T; j += 64)
        out_seq[(size_t)b * T + j] = (j < L) ? sh_seq[j] : 0;
    if (lane == 0) out_len[b] = L;
}

extern "C" void kernel_launch(void* const* d_in, const int* in_sizes, int n_in,
                              void* d_out, int out_size, void* d_ws, size_t ws_size,
                              hipStream_t stream) {
    const float* probs = (const float*)d_in[0];
    const int* lengths = (const int*)d_in[1];
    // d_in[2] = beam_width (fixed 8, compiled in); d_in[3] = blank_index
    const int* blank_p = (const int*)d_in[3];
    const int B = in_sizes[1];
    const int T = in_sizes[0] / (B * VCAB);
    int* out = (int*)d_out;
    ctc_beam_kernel<<<B, 64, 0, stream>>>(probs, lengths, blank_p, out,
                                          out + (size_t)B * T, T);
}